// Round 13
// baseline (292.716 us; speedup 1.0000x reference)
//
#include <hip/hip_runtime.h>
#include <hip/hip_bf16.h>

#define B_ 2
#define S_ 2048
#define H_ 2048
#define NH_ 16
#define NKV_ 4
#define HD_ 128
#define M_ (B_*S_)
#define KVD_ (NKV_*HD_)
#define PSTR 40
#define GRID_MEGA 512

typedef signed char s8;
typedef __attribute__((ext_vector_type(8))) short short8;
typedef __attribute__((ext_vector_type(4))) float f32x4;
typedef __attribute__((ext_vector_type(4))) int int4v;

__device__ __forceinline__ float loadf(const void* p, long i, int isb){
  if (isb) return __bfloat162float(((const __hip_bfloat16*)p)[i]);
  return ((const float*)p)[i];
}

__device__ __forceinline__ unsigned short f2bf(float f){
  union { float f; unsigned u; } v; v.f = f;
  unsigned r = v.u + 0x7FFF + ((v.u >> 16) & 1);
  return (unsigned short)(r >> 16);
}

__device__ __forceinline__ float bf2f(unsigned short b){
  union { unsigned u; float f; } v; v.u = ((unsigned)b) << 16; return v.f;
}

// async global->LDS, 16B/lane; lds dst = wave-uniform base + lane*16
__device__ __forceinline__ void gl2lds16(const void* g, void* l){
  __builtin_amdgcn_global_load_lds(
      (const __attribute__((address_space(1))) void*)g,
      (__attribute__((address_space(3))) void*)l, 16, 0, 0);
}

// ---- launch-stateless grid barrier ----
// Per barrier: {cnt, rel}. Last arriver resets cnt to 0 and bumps the
// monotonic generation rel; waiters snapshot rel BEFORE arriving and spin
// until it changes. After every launch cnt==0 again and rel is merely
// advanced -> graph replay and rocprof counter-replay both see a valid
// initial state (r12 lesson: memset-dependent barriers break under replay).
// Bounded spin converts a genuine deadlock into a wrong answer, not a hang.
__device__ __forceinline__ void gridbar(unsigned* cnt, unsigned* rel, unsigned target){
  __syncthreads();
  if (threadIdx.x == 0){
    unsigned relv = atomicAdd(rel, 0u);   // snapshot before arrival
    __threadfence();
    unsigned old = atomicAdd(cnt, 1u);
    if (old == target - 1u){
      atomicExch(cnt, 0u);                // self-reset for next launch/replay
      __threadfence();
      atomicAdd(rel, 1u);                 // release
    } else {
      unsigned guard = 0;
      while (atomicAdd(rel, 0u) == relv){
        __builtin_amdgcn_s_sleep(2);
        if (++guard > (1u<<24)) break;
      }
    }
    __threadfence();
  }
  __syncthreads();
}

// ---- inline dtype sniffer (shared-scratch variant) ----
__device__ __forceinline__ int detect_isb_s(const unsigned int* x, int* dsh){
  int t = threadIdx.x, cnt = 0;
  #pragma unroll
  for (int i = 0; i < 8; i++){
    unsigned e = (x[t + i*256] >> 7) & 0xFF;
    cnt += (e >= 90 && e <= 150) ? 1 : 0;
  }
  #pragma unroll
  for (int k = 32; k > 0; k >>= 1) cnt += __shfl_down(cnt, k, 64);
  if ((t & 63) == 0) dsh[t >> 6] = cnt;
  __syncthreads();
  int r = (dsh[0] + dsh[1] + dsh[2] + dsh[3]) > 1228;
  __syncthreads();
  return r;
}

// ---- strided |w| scan segment -> atomicAdd into wsum[i] ----
__device__ __forceinline__ void wscan_seg(const void* w, long n, long b0, int nb,
                                          int isb, float* wsum_i, float* sh){
  int t = threadIdx.x;
  float s = 0.f;
  for (long i = b0*256 + t; i < n; i += (long)nb*256) s += fabsf(loadf(w, i, isb));
  sh[t] = s; __syncthreads();
  for (int k = 128; k > 0; k >>= 1){ if (t < k) sh[t] += sh[t+k]; __syncthreads(); }
  if (t == 0) atomicAdd(wsum_i, sh[0]);
  __syncthreads();
}

// ---- strided ternary weight quant segment ----
__device__ __forceinline__ void wquant_seg(const void* w, s8* out, long n, long b0, int nb,
                                           float mean, int isb){
  int t = threadIdx.x;
  float sc = 1.0f / mean;
  for (long i = b0*256 + t; i < n; i += (long)nb*256){
    float v = rintf(loadf(w, i, isb) * sc);
    v = fminf(fmaxf(v, -1.f), 1.f);
    out[i] = (s8)v;
  }
}

// ---- one-row activation quant (typed input x) ----
__device__ __forceinline__ void aquant_row_x(const void* x, int isb, long r,
                                             float* srow, s8* xq, float* sh){
  int t = threadIdx.x;
  long base = r * H_;
  float v[8];
  if (isb){
    uint4 wv = ((const uint4*)((const unsigned short*)x + base))[t];
    unsigned u[4] = {wv.x, wv.y, wv.z, wv.w};
    #pragma unroll
    for (int i = 0; i < 4; i++){
      v[2*i]   = bf2f((unsigned short)(u[i] & 0xFFFF));
      v[2*i+1] = bf2f((unsigned short)(u[i] >> 16));
    }
  } else {
    const float4* p = (const float4*)((const float*)x + base);
    float4 a = p[t*2], b2 = p[t*2+1];
    v[0]=a.x; v[1]=a.y; v[2]=a.z; v[3]=a.w; v[4]=b2.x; v[5]=b2.y; v[6]=b2.z; v[7]=b2.w;
  }
  float mx = 0.f;
  #pragma unroll
  for (int i = 0; i < 8; i++) mx = fmaxf(mx, fabsf(v[i]));
  sh[t] = mx; __syncthreads();
  for (int k = 128; k > 0; k >>= 1){ if (t < k) sh[t] = fmaxf(sh[t], sh[t+k]); __syncthreads(); }
  float s = 127.0f / fmaxf(sh[0], 1e-5f);
  if (t == 0) srow[r] = s;
  unsigned long long pk = 0;
  #pragma unroll
  for (int i = 0; i < 8; i++){
    float q = fminf(fmaxf(rintf(v[i] * s), -128.f), 127.f);
    pk |= ((unsigned long long)(unsigned char)(s8)q) << (8*i);
  }
  *(unsigned long long*)(xq + base + t*8) = pk;
  __syncthreads();
}

// ---- one-row activation quant (bf16 input: attention output) ----
__device__ __forceinline__ void aquant_row_ab(const unsigned short* x, long r,
                                              float* srow, s8* xq, float* sh){
  int t = threadIdx.x;
  long base = r * H_;
  uint4 wv = ((const uint4*)(x + base))[t];
  unsigned u[4] = {wv.x, wv.y, wv.z, wv.w};
  float v[8];
  #pragma unroll
  for (int i = 0; i < 4; i++){
    v[2*i]   = bf2f((unsigned short)(u[i] & 0xFFFF));
    v[2*i+1] = bf2f((unsigned short)(u[i] >> 16));
  }
  float mx = 0.f;
  #pragma unroll
  for (int i = 0; i < 8; i++) mx = fmaxf(mx, fabsf(v[i]));
  sh[t] = mx; __syncthreads();
  for (int k = 128; k > 0; k >>= 1){ if (t < k) sh[t] = fmaxf(sh[t], sh[t+k]); __syncthreads(); }
  float s = 127.0f / fmaxf(sh[0], 1e-5f);
  if (t == 0) srow[r] = s;
  unsigned long long pk = 0;
  #pragma unroll
  for (int i = 0; i < 8; i++){
    float q = fminf(fmaxf(rintf(v[i] * s), -128.f), 127.f);
    pk |= ((unsigned long long)(unsigned char)(s8)q) << (8*i);
  }
  *(unsigned long long*)(xq + base + t*8) = pk;
  __syncthreads();
}

// ---- MFMA int8 GEMM core (r8/r10 form: 128x128 tile, BK=128) ----
// mode 0: RoPE + (1/sqrt(HD))*log2(e) -> bf16 Qb;  mode 3: RoPE -> bf16 Kb
// mode 1: bf16 Vt[b][col][S] (packed 8B stores); mode 2: isb-dtype final out
__device__ __forceinline__ void gemm_core(
      const s8* __restrict__ A, const s8* __restrict__ Bw, s8* As, s8* Bs,
      const float* __restrict__ srow, float mean,
      void* __restrict__ Cout, int N, int mode, int isb,
      unsigned short* __restrict__ Vt,
      const float* __restrict__ ct, const float* __restrict__ st,
      long bcol, long arow){
  int tid = threadIdx.x;
  int wave = tid >> 6, lane = tid & 63;
  int quad = lane >> 4, c = lane & 15;
  int wm = wave >> 1, wn = wave & 1;
  const int K = H_;

  int4v acc[4][4];
  #pragma unroll
  for (int mt = 0; mt < 4; mt++)
    #pragma unroll
    for (int nt = 0; nt < 4; nt++) acc[mt][nt] = (int4v){0,0,0,0};

  int rl = lane >> 2;
  int kq = (lane & 3) ^ ((lane >> 3) & 3);
  int ch0 = wave*2, ch1 = wave*2 + 1;
  long gA0 = (arow + ch0*16 + rl)*(long)K + kq*16;
  long gA1 = (arow + ch1*16 + rl)*(long)K + kq*16;
  long gB0 = (bcol + ch0*16 + rl)*(long)K + kq*16;
  long gB1 = (bcol + ch1*16 + rl)*(long)K + kq*16;

  int sA = quad ^ ((c >> 1) & 3);
  int ntl[4];
  #pragma unroll
  for (int nt = 0; nt < 4; nt++) ntl[nt] = 2*wn + (nt & 1) + 4*(nt >> 1);
  int frA[4], frB[4];
  #pragma unroll
  for (int mt = 0; mt < 4; mt++) frA[mt] = (wm*64 + mt*16 + c)*64 + sA*16;
  #pragma unroll
  for (int nt = 0; nt < 4; nt++) frB[nt] = (ntl[nt]*16 + c)*64 + sA*16;

  for (int k0 = 0; k0 < K; k0 += 128){
    gl2lds16(A  + gA0 + k0,      As        + ch0*1024);
    gl2lds16(A  + gA1 + k0,      As        + ch1*1024);
    gl2lds16(Bw + gB0 + k0,      Bs        + ch0*1024);
    gl2lds16(Bw + gB1 + k0,      Bs        + ch1*1024);
    gl2lds16(A  + gA0 + k0 + 64, As + 8192 + ch0*1024);
    gl2lds16(A  + gA1 + k0 + 64, As + 8192 + ch1*1024);
    gl2lds16(Bw + gB0 + k0 + 64, Bs + 8192 + ch0*1024);
    gl2lds16(Bw + gB1 + k0 + 64, Bs + 8192 + ch1*1024);
    __syncthreads();
    #pragma unroll
    for (int s = 0; s < 2; s++){
      const s8* Ab = As + s*8192;
      const s8* Bb = Bs + s*8192;
      int4v afr[4], bfr[4];
      #pragma unroll
      for (int mt = 0; mt < 4; mt++) afr[mt] = *(const int4v*)&Ab[frA[mt]];
      #pragma unroll
      for (int nt = 0; nt < 4; nt++) bfr[nt] = *(const int4v*)&Bb[frB[nt]];
      #pragma unroll
      for (int mt = 0; mt < 4; mt++)
        #pragma unroll
        for (int nt = 0; nt < 4; nt++)
          acc[mt][nt] = __builtin_amdgcn_mfma_i32_16x16x64_i8(afr[mt], bfr[nt], acc[mt][nt], 0, 0, 0);
    }
    __syncthreads();
  }

  if (mode == 0 || mode == 3){
    unsigned short* Ob = (unsigned short*)Cout;
    #pragma unroll
    for (int mt = 0; mt < 4; mt++){
      #pragma unroll
      for (int r = 0; r < 4; r++){
        long grow = arow + wm*64 + mt*16 + quad*4 + r;
        float sc = mean / srow[grow];
        // fold softmax scale AND log2(e): 2^-3.5 * log2(e) = 0.12751743
        if (mode == 0) sc *= 0.12751743f;
        int pos = (int)(grow & (S_-1));
        #pragma unroll
        for (int p = 0; p < 2; p++){
          int col_lo = (int)bcol + (2*wn + p)*16 + c;
          int d = col_lo & 63;
          float cv = ct[pos*64 + d], sv = st[pos*64 + d];
          float vlo = acc[mt][p][r]   * sc;
          float vhi = acc[mt][p+2][r] * sc;
          Ob[grow*(long)N + col_lo]      = f2bf(vlo*cv - vhi*sv);
          Ob[grow*(long)N + col_lo + 64] = f2bf(vhi*cv + vlo*sv);
        }
      }
    }
  } else if (mode == 1){
    #pragma unroll
    for (int mt = 0; mt < 4; mt++){
      long grow0 = arow + wm*64 + mt*16 + quad*4;
      float s0 = mean / srow[grow0];
      float s1 = mean / srow[grow0+1];
      float s2 = mean / srow[grow0+2];
      float s3 = mean / srow[grow0+3];
      long bb = grow0 >> 11; int sI = (int)(grow0 & (S_-1));
      unsigned short* base = Vt + bb*(long)KVD_*S_ + sI;
      #pragma unroll
      for (int nt = 0; nt < 4; nt++){
        float v0 = acc[mt][nt][0]*s0, v1 = acc[mt][nt][1]*s1;
        float v2 = acc[mt][nt][2]*s2, v3 = acc[mt][nt][3]*s3;
        unsigned lo, hi;
        asm("v_cvt_pk_bf16_f32 %0, %1, %2" : "=v"(lo) : "v"(v0), "v"(v1));
        asm("v_cvt_pk_bf16_f32 %0, %1, %2" : "=v"(hi) : "v"(v2), "v"(v3));
        uint2 pk; pk.x = lo; pk.y = hi;
        *(uint2*)(base + (long)(bcol + ntl[nt]*16 + c)*S_) = pk;  // 4 rows, 8B
      }
    }
  } else {
    #pragma unroll
    for (int mt = 0; mt < 4; mt++){
      #pragma unroll
      for (int r = 0; r < 4; r++){
        long grow = arow + wm*64 + mt*16 + quad*4 + r;
        float sc = mean / srow[grow];
        long cb = grow*(long)N + bcol + c;
        if (isb){
          __hip_bfloat16* o = (__hip_bfloat16*)Cout;
          #pragma unroll
          for (int nt = 0; nt < 4; nt++)
            o[cb + ntl[nt]*16] = __float2bfloat16(acc[mt][nt][r] * sc);
        } else {
          float* o = (float*)Cout;
          #pragma unroll
          for (int nt = 0; nt < 4; nt++)
            o[cb + ntl[nt]*16] = acc[mt][nt][r] * sc;
        }
      }
    }
  }
}

// ---- qkv tile dispatcher (XCD clustering, r10 mapping, 768 tiles) ----
__device__ __forceinline__ void qkv_tile(int lid, const s8* xq,
      const s8* wqq, const s8* wkq, const s8* wvq,
      const float* srow, const float* wsum,
      unsigned short* Qb, unsigned short* Kb, unsigned short* Vt,
      const float* ct, const float* st, s8* As, s8* Bs){
  int xcd = lid & 7;
  int rem = lid >> 3;          // 0..95
  int by  = xcd*4 + (rem & 3); // 0..31
  int bx  = rem >> 2;          // 0..23
  const float cq = (float)((long)H_*H_), ck = (float)((long)KVD_*H_);
  const s8* Bw; void* Cout; unsigned short* vt = nullptr;
  int N, mode; float mean; long bcol;
  if (bx < 16){
    Bw = wqq; Cout = Qb; N = H_;   mode = 0; mean = fmaxf(wsum[0]/cq, 1e-5f);  bcol = (long)bx*128;
  } else if (bx < 20){
    Bw = wkq; Cout = Kb; N = KVD_; mode = 3; mean = fmaxf(wsum[1]/ck, 1e-5f); bcol = (long)(bx-16)*128;
  } else {
    Bw = wvq; Cout = nullptr; vt = Vt; N = KVD_; mode = 1; mean = fmaxf(wsum[2]/ck, 1e-5f); bcol = (long)(bx-20)*128;
  }
  gemm_core(xq, Bw, As, Bs, srow, mean, Cout, N, mode, 0, vt, ct, st, bcol, (long)by*128);
}

// ---- output-gemm tile dispatcher (512 tiles) ----
__device__ __forceinline__ void o_tile(int lid, const s8* aq, const s8* woq,
      const float* srow, const float* wsum, int isb, void* out,
      const float* ct, const float* st, s8* As, s8* Bs){
  int xcd = lid & 7;
  int rem = lid >> 3;          // 0..63
  int by  = xcd*4 + (rem & 3); // 0..31
  int bx  = rem >> 2;          // 0..15
  float mean = fmaxf(wsum[3] / (float)((long)H_*H_), 1e-5f);
  gemm_core(aq, woq, As, Bs, srow, mean, out, H_, 2, isb, nullptr, ct, st,
            (long)bx*128, (long)by*128);
}

// ---- attention body: r2/r10 configuration VERBATIM, parameterized ----
__device__ __forceinline__ void attn_body(int win, int kvh, int b,
    const unsigned short* __restrict__ Qb, const unsigned short* __restrict__ Kb,
    const unsigned short* __restrict__ Vt, unsigned short* __restrict__ ob,
    unsigned short (*Ks)[64*128], unsigned short* Vs, unsigned short (*Ps)[16*PSTR]){
  int wid = threadIdx.x >> 6, lane = threadIdx.x & 63;
  int quad = lane >> 4, c = lane & 15;
  if (b == 1) win = (S_/32 - 1) - win;   // pair big+small windows per CU
  int h = kvh*4 + wid;
  int q0 = win*32;

  short8 qf[2][4];
  #pragma unroll
  for (int t0 = 0; t0 < 2; t0++)
    #pragma unroll
    for (int f = 0; f < 4; f++)
      qf[t0][f] = *(const short8*)(Qb + ((long)(b*S_ + q0 + t0*16 + c)*NH_ + h)*HD_ + f*32 + quad*8);

  const unsigned short* Kg = Kb + (long)b*S_*KVD_ + kvh*HD_;
  const unsigned short* Vg = Vt + ((long)b*KVD_ + kvh*HD_)*S_;

  f32x4 o[2][8], ol[2];
  #pragma unroll
  for (int t0 = 0; t0 < 2; t0++){
    #pragma unroll
    for (int i = 0; i < 8; i++) o[t0][i] = (f32x4){0.f,0.f,0.f,0.f};
    ol[t0] = (f32x4){0.f,0.f,0.f,0.f};
  }
  short8 ones;
  #pragma unroll
  for (int i = 0; i < 8; i++) ones[i] = (short)0x3F80;

  int skey = lane >> 4;
  int kslot = lane & 15;
  int vrow = lane >> 3;
  int vslot = lane & 7;

  int nk = q0 + 32;
  // prologue: stage K(0) -> Ks[0]
  #pragma unroll
  for (int i = 0; i < 4; i++){
    int kk = wid*16 + i*4;
    int key = kk + skey;
    int g = kslot ^ (key & 15);
    gl2lds16(Kg + (long)key*KVD_ + g*8, &Ks[0][kk*128]);
  }

  int buf = 0;
  for (int kc = 0; kc < nk; kc += 64, buf ^= 1){
    __syncthreads();   // A: K(kc) staged; all waves done with prior Vs reads
    // stage V(kc) — latency hidden by QK phase below
    #pragma unroll
    for (int i = 0; i < 4; i++){
      int rr = wid*32 + i*8;
      int hd = rr + vrow;
      int g = vslot ^ (hd & 7);
      gl2lds16(Vg + (long)hd*S_ + kc + g*8, &Vs[rr*64]);
    }

    // ---- QK^T from Ks[buf], SWAPPED: s[t0][kt] = K_tile^T x Q_tile
    f32x4 s[2][4];
    #pragma unroll
    for (int t0 = 0; t0 < 2; t0++)
      #pragma unroll
      for (int kt = 0; kt < 4; kt++) s[t0][kt] = (f32x4){0.f,0.f,0.f,0.f};
    #pragma unroll
    for (int kt = 0; kt < 4; kt++){
      short8 kf4[4];
      #pragma unroll
      for (int f = 0; f < 4; f++)
        kf4[f] = *(const short8*)&Ks[buf][(kt*16 + c)*128 + ((f*4 + quad) ^ c)*8];
      #pragma unroll
      for (int t0 = 0; t0 < 2; t0++)
        #pragma unroll
        for (int f = 0; f < 4; f++)
          s[t0][kt] = __builtin_amdgcn_mfma_f32_16x16x32_bf16(kf4[f], qf[t0][f], s[t0][kt], 0, 0, 0);
    }
    // causal mask in transposed layout
    #pragma unroll
    for (int t0 = 0; t0 < 2; t0++){
      int qv = q0 + t0*16 + c;
      if (kc + 63 > q0 + t0*16){
        #pragma unroll
        for (int kt = 0; kt < 4; kt++){
          #pragma unroll
          for (int r = 0; r < 4; r++){
            int key = kc + kt*16 + quad*4 + r;
            if (key > qv) s[t0][kt][r] = -1e30f;
          }
        }
      }
    }

    __syncthreads();   // B: V(kc) staged (hidden by QK above)

    // prefetch K(kc+64) -> Ks[buf^1]; drained at next barrier A (hidden by PV)
    if (kc + 64 < nk){
      #pragma unroll
      for (int i = 0; i < 4; i++){
        int kk = wid*16 + i*4;
        int key = kk + skey;
        int g = kslot ^ (key & 15);
        gl2lds16(Kg + (long)(kc + 64 + key)*KVD_ + g*8, &Ks[buf^1][kk*128]);
      }
    }

    // ---- exp2 + packed P write + PV
    #pragma unroll
    for (int pp = 0; pp < 2; pp++){
      short8 vf[8];
      #pragma unroll
      for (int nt = 0; nt < 8; nt++)
        vf[nt] = *(const short8*)&Vs[(nt*16 + c)*64 + ((pp*4 + quad) ^ (c & 7))*8];
      #pragma unroll
      for (int t0 = 0; t0 < 2; t0++){
        #pragma unroll
        for (int tk = 0; tk < 2; tk++){
          f32x4 sv = s[t0][pp*2 + tk];
          float e0 = exp2f(sv[0]), e1 = exp2f(sv[1]);
          float e2 = exp2f(sv[2]), e3 = exp2f(sv[3]);
          unsigned w0, w1;
          asm("v_cvt_pk_bf16_f32 %0, %1, %2" : "=v"(w0) : "v"(e0), "v"(e1));
          asm("v_cvt_pk_bf16_f32 %0, %1, %2" : "=v"(w1) : "v"(e2), "v"(e3));
          uint2 pkv; pkv.x = w0; pkv.y = w1;
          *(uint2*)&Ps[wid][c*PSTR + tk*16 + quad*4] = pkv;
        }
        short8 pf = *(const short8*)&Ps[wid][c*PSTR + quad*8];
        #pragma unroll
        for (int nt = 0; nt < 8; nt++)
          o[t0][nt] = __builtin_amdgcn_mfma_f32_16x16x32_bf16(pf, vf[nt], o[t0][nt], 0, 0, 0);
        ol[t0] = __builtin_amdgcn_mfma_f32_16x16x32_bf16(pf, ones, ol[t0], 0, 0, 0);
      }
    }
  }

  #pragma unroll
  for (int t0 = 0; t0 < 2; t0++){
    float il[4];
    #pragma unroll
    for (int r = 0; r < 4; r++) il[r] = 1.0f / ol[t0][r];
    #pragma unroll
    for (int nt = 0; nt < 8; nt++)
      #pragma unroll
      for (int r = 0; r < 4; r++)
        ob[((long)(b*S_ + q0 + t0*16 + quad*4 + r))*H_ + h*HD_ + nt*16 + c] = f2bf(o[t0][nt][r]*il[r]);
  }
}

// ================= fallback (r10) kernels =================

__global__ void k_prep_aq(const void* x,
                          const void* Wq, const void* Wk, const void* Wv, const void* Wo,
                          float* wsum, float* ct, float* st,
                          float* srow, s8* xq){
  __shared__ __align__(16) float sh[256];
  __shared__ int dsh[4];
  int isb = detect_isb_s((const unsigned int*)x, dsh);
  int bid = blockIdx.x, t = threadIdx.x;
  if (bid < 2048){
    if (t < 64){
      float inv = exp2f(-(float)t * 0.20762050593045952f);  // 10000^(-d/64)
      float a = (float)bid * inv;
      float sn, cs; sincosf(a, &sn, &cs);
      ct[bid*64 + t] = cs; st[bid*64 + t] = sn;
    }
    if (bid < 768)       wscan_seg(Wq, (long)H_*H_,   bid,      768, isb, &wsum[0], sh);
    else if (bid < 1024) wscan_seg(Wk, (long)KVD_*H_, bid-768,  256, isb, &wsum[1], sh);
    else if (bid < 1280) wscan_seg(Wv, (long)KVD_*H_, bid-1024, 256, isb, &wsum[2], sh);
    else                 wscan_seg(Wo, (long)H_*H_,   bid-1280, 768, isb, &wsum[3], sh);
  } else {
    aquant_row_x(x, isb, bid - 2048, srow, xq, sh);
  }
}

__global__ void k_wquant_all(const void* Wq, const void* Wk, const void* Wv, const void* Wo,
                             const void* x, const float* wsum,
                             s8* oq, s8* ok, s8* ov, s8* oo){
  __shared__ int dsh[4];
  int isb = detect_isb_s((const unsigned int*)x, dsh);
  int bid = blockIdx.x;
  const float cq = (float)((long)H_*H_), ck = (float)((long)KVD_*H_);
  if (bid < 1024)      wquant_seg(Wq, oq, (long)H_*H_,   bid,      1024, fmaxf(wsum[0]/cq, 1e-5f), isb);
  else if (bid < 1280) wquant_seg(Wk, ok, (long)KVD_*H_, bid-1024, 256,  fmaxf(wsum[1]/ck, 1e-5f), isb);
  else if (bid < 1536) wquant_seg(Wv, ov, (long)KVD_*H_, bid-1280, 256,  fmaxf(wsum[2]/ck, 1e-5f), isb);
  else                 wquant_seg(Wo, oo, (long)H_*H_,   bid-1536, 1024, fmaxf(wsum[3]/cq, 1e-5f), isb);
}

__global__ void k_aquant_bf16(const unsigned short* __restrict__ x,
                              float* __restrict__ srow, s8* __restrict__ xq){
  __shared__ __align__(16) float sh[256];
  aquant_row_ab(x, blockIdx.x, srow, xq, sh);
}

__global__ __launch_bounds__(256, 2) void k_gemm_qkv(
      const s8* __restrict__ xq,
      const s8* __restrict__ wqq, const s8* __restrict__ wkq, const s8* __restrict__ wvq,
      const float* __restrict__ srow, const float* __restrict__ wsum,
      unsigned short* __restrict__ Qb, unsigned short* __restrict__ Kb,
      unsigned short* __restrict__ Vt,
      const float* __restrict__ ct, const float* __restrict__ st){
  __shared__ __align__(16) s8 As[2*128*64];
  __shared__ __align__(16) s8 Bs[2*128*64];
  qkv_tile(blockIdx.x, xq, wqq, wkq, wvq, srow, wsum, Qb, Kb, Vt, ct, st, As, Bs);
}

__global__ __launch_bounds__(256, 2) void k_gemm_o(
      const s8* __restrict__ aq, const s8* __restrict__ woq,
      const float* __restrict__ srow, const float* __restrict__ wsum,
      const void* __restrict__ x, void* __restrict__ out,
      const float* __restrict__ ct, const float* __restrict__ st){
  __shared__ __align__(16) s8 As[2*128*64];
  __shared__ __align__(16) s8 Bs[2*128*64];
  __shared__ int dsh[4];
  int isb = detect_isb_s((const unsigned int*)x, dsh);
  o_tile(blockIdx.x, aq, woq, srow, wsum, isb, out, ct, st, As, Bs);
}

__global__ __launch_bounds__(256) void k_attn_mfma(const unsigned short* __restrict__ Qb,
    const unsigned short* __restrict__ Kb, const unsigned short* __restrict__ Vt,
    unsigned short* __restrict__ ob){
  __shared__ __align__(16) unsigned short Ks[2][64*128];
  __shared__ __align__(16) unsigned short Vs[128*64];
  __shared__ __align__(16) unsigned short Ps[4][16*PSTR];
  attn_body(blockIdx.x, blockIdx.y, blockIdx.z, Qb, Kb, Vt, ob, Ks, Vs, Ps);
}

// ================= mega-kernel v2: 2 blocks/CU, stateless barriers =========
// r12 lesson: launch_bounds(256,3) capped the UNIFIED file at ~170 < attn's
// ~200 (128 arch + 72 acc) -> 50-reg spill -> 1GB scratch. v2: grid 512 =
// 2 blocks/CU (launch_bounds(256,2) -> 256-reg cap, same residency attn has
// standalone, zero spill). P2 loops 768 qkv tiles over 512 blocks (2 rounds
// for bid<256 — identical effective schedule to the 768-block launch at
// 2/CU). Phase maps keep b-pairing (bid/bid+256 share a CU) + XCD clustering.
struct SmemAttn { unsigned short Ks[2][64*128]; unsigned short Vs[128*64]; unsigned short Ps[4][16*PSTR]; };
struct SmemGemm { s8 As[2*128*64]; s8 Bs[2*128*64]; };

__global__ __launch_bounds__(256, 2) void k_mega(
    const void* x, const void* Wq, const void* Wk, const void* Wv, const void* Wo,
    float* wsum, unsigned* bars, float* ct, float* st, float* s_x, s8* xq,
    s8* wqq, s8* wkq, s8* wvq, s8* woq,
    unsigned short* Qb, unsigned short* Kb, unsigned short* Vt,
    unsigned short* ab, float* s_a, s8* aq, void* out){
  __shared__ __align__(16) unsigned char smem[sizeof(SmemAttn)];
  float* sh = (float*)smem;
  int*  dsh = (int*)(smem + 1024);
  int bid = blockIdx.x, t = threadIdx.x;
  int isb = detect_isb_s((const unsigned int*)x, dsh);

  // ---- P0: RoPE table + weight |w| sums + input activation quant ----
  {
    long idx = (long)bid*256 + t;      // 512*256 = 131072 = S_*64 exactly
    int pos = (int)(idx >> 6), d = (int)(idx & 63);
    float inv = exp2f(-(float)d * 0.20762050593045952f);
    float a = (float)pos * inv;
    float sn, cs; sincosf(a, &sn, &cs);
    ct[pos*64 + d] = cs; st[pos*64 + d] = sn;
    if (bid < 192)      wscan_seg(Wq, (long)H_*H_,   bid,     192, isb, &wsum[0], sh);
    else if (bid < 256) wscan_seg(Wk, (long)KVD_*H_, bid-192, 64,  isb, &wsum[1], sh);
    else if (bid < 320) wscan_seg(Wv, (long)KVD_*H_, bid-256, 64,  isb, &wsum[2], sh);
    else                wscan_seg(Wo, (long)H_*H_,   bid-320, 192, isb, &wsum[3], sh);
    for (long r = bid; r < M_; r += GRID_MEGA) aquant_row_x(x, isb, r, s_x, xq, sh);
  }
  gridbar(&bars[0], &bars[1], GRID_MEGA);

  // ---- P1: ternary weight quant ----
  {
    const float cq = (float)((long)H_*H_), ck = (float)((long)KVD_*H_);
    if (bid < 192)      wquant_seg(Wq, wqq, (long)H_*H_,   bid,     192, fmaxf(wsum[0]/cq, 1e-5f), isb);
    else if (bid < 256) wquant_seg(Wk, wkq, (long)KVD_*H_, bid-192, 64,  fmaxf(wsum[1]/ck, 1e-5f), isb);
    else if (bid < 320) wquant_seg(Wv, wvq, (long)KVD_*H_, bid-256, 64,  fmaxf(wsum[2]/ck, 1e-5f), isb);
    else                wquant_seg(Wo, woq, (long)H_*H_,   bid-320, 192, fmaxf(wsum[3]/cq, 1e-5f), isb);
  }
  gridbar(&bars[2], &bars[3], GRID_MEGA);

  // ---- P2: QKV GEMM (768 tiles over 512 blocks, tile += 512) ----
  {
    SmemGemm* sg = (SmemGemm*)smem;
    for (int tile = bid; tile < 768; tile += GRID_MEGA){
      qkv_tile(tile, xq, wqq, wkq, wvq, s_x, wsum, Qb, Kb, Vt, ct, st, sg->As, sg->Bs);
      __syncthreads();
    }
  }
  gridbar(&bars[4], &bars[5], GRID_MEGA);

  // ---- P3: attention (512 tiles; bid & bid+256 share a CU = b-pairing) ----
  {
    SmemAttn* sa = (SmemAttn*)smem;
    attn_body(bid & 63, (bid >> 6) & 3, bid >> 8, Qb, Kb, Vt, ab, sa->Ks, sa->Vs, sa->Ps);
  }
  gridbar(&bars[6], &bars[7], GRID_MEGA);

  // ---- P4: attention-output activation quant ----
  for (long r = bid; r < M_; r += GRID_MEGA) aquant_row_ab(ab, r, s_a, aq, sh);
  gridbar(&bars[8], &bars[9], GRID_MEGA);

  // ---- P5: output GEMM (512 tiles) ----
  {
    SmemGemm* sg = (SmemGemm*)smem;
    o_tile(bid, aq, woq, s_a, wsum, isb, out, ct, st, sg->As, sg->Bs);
  }
}

extern "C" void kernel_launch(void* const* d_in, const int* in_sizes, int n_in,
                              void* d_out, int out_size, void* d_ws, size_t ws_size,
                              hipStream_t stream){
  (void)in_sizes; (void)n_in; (void)out_size; (void)ws_size;
  const void* x  = d_in[0];
  const void* Wq = d_in[2];
  const void* Wk = d_in[3];
  const void* Wv = d_in[4];
  const void* Wo = d_in[5];
  char* ws = (char*)d_ws;
  size_t o = 0;
  auto alloc = [&](size_t b){ size_t r = o; o += (b + 255) & ~(size_t)255; return r; };
  size_t META = alloc(256);
  float* wsum = (float*)(ws + META);
  unsigned* bars = (unsigned*)(ws + META + 64);   // 5 x {cnt, rel}
  float* s_x = (float*)(ws + alloc((size_t)M_*4));
  float* s_a = (float*)(ws + alloc((size_t)M_*4));
  float* ct  = (float*)(ws + alloc((size_t)S_*64*4));
  float* st  = (float*)(ws + alloc((size_t)S_*64*4));
  s8* xq  = (s8*)(ws + alloc((size_t)M_*H_));
  s8* wqq = (s8*)(ws + alloc((size_t)H_*H_));
  s8* wkq = (s8*)(ws + alloc((size_t)KVD_*H_));
  s8* wvq = (s8*)(ws + alloc((size_t)KVD_*H_));
  s8* woq = (s8*)(ws + alloc((size_t)H_*H_));
  unsigned short* Qb = (unsigned short*)(ws + alloc((size_t)M_*NH_*HD_*2));
  unsigned short* Kb = (unsigned short*)(ws + alloc((size_t)M_*KVD_*2));
  unsigned short* Vt = (unsigned short*)(ws + alloc((size_t)M_*KVD_*2));
  unsigned short* ab = (unsigned short*)(ws + alloc((size_t)M_*H_*2));
  s8* aq = (s8*)(ws + alloc((size_t)M_*H_));   // separate from xq (mega path)
  void* outp = d_out;

  // zero wsum (+ first-ever barrier init; barriers are self-resetting after)
  hipMemsetAsync(ws + META, 0, 256, stream);

  // host-side introspection guards (graph-safe; r12 lesson: also check spill)
  static int mega_ok = -1;
  if (mega_ok < 0){
    hipFuncAttributes fa{};
    int occ = 0;
    hipError_t e1 = hipFuncGetAttributes(&fa, (const void*)k_mega);
    hipError_t e2 = hipOccupancyMaxActiveBlocksPerMultiprocessor(&occ, (const void*)k_mega, 256, 0);
    mega_ok = (e1 == hipSuccess && e2 == hipSuccess &&
               occ >= 2 && fa.numRegs > 0 && fa.localSizeBytes == 0) ? 1 : 0;
  }

  if (mega_ok == 1){
    k_mega<<<GRID_MEGA, 256, 0, stream>>>(
        x, Wq, Wk, Wv, Wo, wsum, bars, ct, st, s_x, xq,
        wqq, wkq, wvq, woq, Qb, Kb, Vt, ab, s_a, aq, outp);
    return;
  }

  // fallback: r10 chain (289.7us measured)
  k_prep_aq<<<2048 + M_, 256, 0, stream>>>(x, Wq, Wk, Wv, Wo, wsum, ct, st, s_x, xq);
  k_wquant_all<<<2560, 256, 0, stream>>>(Wq, Wk, Wv, Wo, x, wsum, wqq, wkq, wvq, woq);
  k_gemm_qkv<<<768, 256, 0, stream>>>(xq, wqq, wkq, wvq, s_x, wsum, Qb, Kb, Vt, ct, st);
  dim3 ga(S_/32, NKV_, B_);
  k_attn_mfma<<<ga, 256, 0, stream>>>(Qb, Kb, Vt, ab);
  k_aquant_bf16<<<M_, 256, 0, stream>>>(ab, s_a, aq);
  k_gemm_o<<<512, 256, 0, stream>>>(aq, woq, s_a, wsum, x, d_out, ct, st);
}

// Round 14
// 282.595 us; speedup vs baseline: 1.0358x; 1.0358x over previous
//
#include <hip/hip_runtime.h>
#include <hip/hip_bf16.h>

#define B_ 2
#define S_ 2048
#define H_ 2048
#define NH_ 16
#define NKV_ 4
#define HD_ 128
#define M_ (B_*S_)
#define KVD_ (NKV_*HD_)
#define PSTR 40

typedef signed char s8;
typedef __attribute__((ext_vector_type(8))) short short8;
typedef __attribute__((ext_vector_type(4))) float f32x4;
typedef __attribute__((ext_vector_type(4))) int int4v;

__device__ __forceinline__ float loadf(const void* p, long i, int isb){
  if (isb) return __bfloat162float(((const __hip_bfloat16*)p)[i]);
  return ((const float*)p)[i];
}

__device__ __forceinline__ unsigned short f2bf(float f){
  union { float f; unsigned u; } v; v.f = f;
  unsigned r = v.u + 0x7FFF + ((v.u >> 16) & 1);
  return (unsigned short)(r >> 16);
}

__device__ __forceinline__ float bf2f(unsigned short b){
  union { unsigned u; float f; } v; v.u = ((unsigned)b) << 16; return v.f;
}

// async global->LDS, 16B/lane; lds dst = wave-uniform base + lane*16
__device__ __forceinline__ void gl2lds16(const void* g, void* l){
  __builtin_amdgcn_global_load_lds(
      (const __attribute__((address_space(1))) void*)g,
      (__attribute__((address_space(3))) void*)l, 16, 0, 0);
}

// ---- inline dtype sniffer ----
__device__ __forceinline__ int detect_isb_s(const unsigned int* x, int* dsh){
  int t = threadIdx.x, cnt = 0;
  #pragma unroll
  for (int i = 0; i < 8; i++){
    unsigned e = (x[t + i*256] >> 7) & 0xFF;
    cnt += (e >= 90 && e <= 150) ? 1 : 0;
  }
  #pragma unroll
  for (int k = 32; k > 0; k >>= 1) cnt += __shfl_down(cnt, k, 64);
  if ((t & 63) == 0) dsh[t >> 6] = cnt;
  __syncthreads();
  int r = (dsh[0] + dsh[1] + dsh[2] + dsh[3]) > 1228;
  __syncthreads();
  return r;
}

// ---- vectorized |w| scan segment (G13: 8 elems/lane, 16-32B loads) ----
// n divisible by nb*256*8 coverage: all segment sizes are multiples of 2048*nb.
__device__ __forceinline__ void wscan_seg(const void* w, long n, long b0, int nb,
                                          int isb, float* wsum_i, float* sh){
  int t = threadIdx.x;
  float s = 0.f;
  long stride = (long)nb*256*8;
  if (isb){
    const unsigned short* wp = (const unsigned short*)w;
    for (long i = (b0*256 + t)*8; i < n; i += stride){
      short8 v = *(const short8*)(wp + i);
      #pragma unroll
      for (int j = 0; j < 8; j++) s += fabsf(bf2f((unsigned short)v[j]));
    }
  } else {
    const float* wp = (const float*)w;
    for (long i = (b0*256 + t)*8; i < n; i += stride){
      float4 a = *(const float4*)(wp + i);
      float4 b = *(const float4*)(wp + i + 4);
      s += fabsf(a.x)+fabsf(a.y)+fabsf(a.z)+fabsf(a.w)
         + fabsf(b.x)+fabsf(b.y)+fabsf(b.z)+fabsf(b.w);
    }
  }
  sh[t] = s; __syncthreads();
  for (int k = 128; k > 0; k >>= 1){ if (t < k) sh[t] += sh[t+k]; __syncthreads(); }
  if (t == 0) atomicAdd(wsum_i, sh[0]);
  __syncthreads();
}

// ---- vectorized ternary weight quant: 8 elems/lane, ONE 8B store ----
__device__ __forceinline__ void wquant_seg(const void* w, s8* out, long n, long b0, int nb,
                                           float mean, int isb){
  int t = threadIdx.x;
  float sc = 1.0f / mean;
  long stride = (long)nb*256*8;
  for (long i = (b0*256 + t)*8; i < n; i += stride){
    float v[8];
    if (isb){
      short8 wv = *(const short8*)((const unsigned short*)w + i);
      #pragma unroll
      for (int j = 0; j < 8; j++) v[j] = bf2f((unsigned short)wv[j]);
    } else {
      float4 a = *(const float4*)((const float*)w + i);
      float4 b = *(const float4*)((const float*)w + i + 4);
      v[0]=a.x; v[1]=a.y; v[2]=a.z; v[3]=a.w; v[4]=b.x; v[5]=b.y; v[6]=b.z; v[7]=b.w;
    }
    unsigned long long pk = 0;
    #pragma unroll
    for (int j = 0; j < 8; j++){
      float q = fminf(fmaxf(rintf(v[j] * sc), -1.f), 1.f);
      pk |= ((unsigned long long)(unsigned char)(s8)q) << (8*j);
    }
    *(unsigned long long*)(out + i) = pk;
  }
}

// ---- one-row activation quant (typed input x) ----
__device__ __forceinline__ void aquant_row_x(const void* x, int isb, long r,
                                             float* srow, s8* xq, float* sh){
  int t = threadIdx.x;
  long base = r * H_;
  float v[8];
  if (isb){
    uint4 wv = ((const uint4*)((const unsigned short*)x + base))[t];
    unsigned u[4] = {wv.x, wv.y, wv.z, wv.w};
    #pragma unroll
    for (int i = 0; i < 4; i++){
      v[2*i]   = bf2f((unsigned short)(u[i] & 0xFFFF));
      v[2*i+1] = bf2f((unsigned short)(u[i] >> 16));
    }
  } else {
    const float4* p = (const float4*)((const float*)x + base);
    float4 a = p[t*2], b2 = p[t*2+1];
    v[0]=a.x; v[1]=a.y; v[2]=a.z; v[3]=a.w; v[4]=b2.x; v[5]=b2.y; v[6]=b2.z; v[7]=b2.w;
  }
  float mx = 0.f;
  #pragma unroll
  for (int i = 0; i < 8; i++) mx = fmaxf(mx, fabsf(v[i]));
  sh[t] = mx; __syncthreads();
  for (int k = 128; k > 0; k >>= 1){ if (t < k) sh[t] = fmaxf(sh[t], sh[t+k]); __syncthreads(); }
  float s = 127.0f / fmaxf(sh[0], 1e-5f);
  if (t == 0) srow[r] = s;
  unsigned long long pk = 0;
  #pragma unroll
  for (int i = 0; i < 8; i++){
    float q = fminf(fmaxf(rintf(v[i] * s), -128.f), 127.f);
    pk |= ((unsigned long long)(unsigned char)(s8)q) << (8*i);
  }
  *(unsigned long long*)(xq + base + t*8) = pk;
  __syncthreads();
}

// ---- one-row activation quant (bf16 input: attention output) ----
__device__ __forceinline__ void aquant_row_ab(const unsigned short* x, long r,
                                              float* srow, s8* xq, float* sh){
  int t = threadIdx.x;
  long base = r * H_;
  uint4 wv = ((const uint4*)(x + base))[t];
  unsigned u[4] = {wv.x, wv.y, wv.z, wv.w};
  float v[8];
  #pragma unroll
  for (int i = 0; i < 4; i++){
    v[2*i]   = bf2f((unsigned short)(u[i] & 0xFFFF));
    v[2*i+1] = bf2f((unsigned short)(u[i] >> 16));
  }
  float mx = 0.f;
  #pragma unroll
  for (int i = 0; i < 8; i++) mx = fmaxf(mx, fabsf(v[i]));
  sh[t] = mx; __syncthreads();
  for (int k = 128; k > 0; k >>= 1){ if (t < k) sh[t] = fmaxf(sh[t], sh[t+k]); __syncthreads(); }
  float s = 127.0f / fmaxf(sh[0], 1e-5f);
  if (t == 0) srow[r] = s;
  unsigned long long pk = 0;
  #pragma unroll
  for (int i = 0; i < 8; i++){
    float q = fminf(fmaxf(rintf(v[i] * s), -128.f), 127.f);
    pk |= ((unsigned long long)(unsigned char)(s8)q) << (8*i);
  }
  *(unsigned long long*)(xq + base + t*8) = pk;
  __syncthreads();
}

// ---- MFMA int8 GEMM core (r8/r10 form: 128x128 tile, BK=128) ----
// mode 0: RoPE + (1/sqrt(HD))*log2(e) -> bf16 Qb;  mode 3: RoPE -> bf16 Kb
// mode 1: bf16 Vt[b][col][S] (packed 8B stores); mode 2: isb-dtype final out
__device__ __forceinline__ void gemm_core(
      const s8* __restrict__ A, const s8* __restrict__ Bw, s8* As, s8* Bs,
      const float* __restrict__ srow, float mean,
      void* __restrict__ Cout, int N, int mode, int isb,
      unsigned short* __restrict__ Vt,
      const float* __restrict__ ct, const float* __restrict__ st,
      long bcol, long arow){
  int tid = threadIdx.x;
  int wave = tid >> 6, lane = tid & 63;
  int quad = lane >> 4, c = lane & 15;
  int wm = wave >> 1, wn = wave & 1;
  const int K = H_;

  int4v acc[4][4];
  #pragma unroll
  for (int mt = 0; mt < 4; mt++)
    #pragma unroll
    for (int nt = 0; nt < 4; nt++) acc[mt][nt] = (int4v){0,0,0,0};

  int rl = lane >> 2;
  int kq = (lane & 3) ^ ((lane >> 3) & 3);
  int ch0 = wave*2, ch1 = wave*2 + 1;
  long gA0 = (arow + ch0*16 + rl)*(long)K + kq*16;
  long gA1 = (arow + ch1*16 + rl)*(long)K + kq*16;
  long gB0 = (bcol + ch0*16 + rl)*(long)K + kq*16;
  long gB1 = (bcol + ch1*16 + rl)*(long)K + kq*16;

  int sA = quad ^ ((c >> 1) & 3);
  int ntl[4];
  #pragma unroll
  for (int nt = 0; nt < 4; nt++) ntl[nt] = 2*wn + (nt & 1) + 4*(nt >> 1);
  int frA[4], frB[4];
  #pragma unroll
  for (int mt = 0; mt < 4; mt++) frA[mt] = (wm*64 + mt*16 + c)*64 + sA*16;
  #pragma unroll
  for (int nt = 0; nt < 4; nt++) frB[nt] = (ntl[nt]*16 + c)*64 + sA*16;

  for (int k0 = 0; k0 < K; k0 += 128){
    gl2lds16(A  + gA0 + k0,      As        + ch0*1024);
    gl2lds16(A  + gA1 + k0,      As        + ch1*1024);
    gl2lds16(Bw + gB0 + k0,      Bs        + ch0*1024);
    gl2lds16(Bw + gB1 + k0,      Bs        + ch1*1024);
    gl2lds16(A  + gA0 + k0 + 64, As + 8192 + ch0*1024);
    gl2lds16(A  + gA1 + k0 + 64, As + 8192 + ch1*1024);
    gl2lds16(Bw + gB0 + k0 + 64, Bs + 8192 + ch0*1024);
    gl2lds16(Bw + gB1 + k0 + 64, Bs + 8192 + ch1*1024);
    __syncthreads();
    #pragma unroll
    for (int s = 0; s < 2; s++){
      const s8* Ab = As + s*8192;
      const s8* Bb = Bs + s*8192;
      int4v afr[4], bfr[4];
      #pragma unroll
      for (int mt = 0; mt < 4; mt++) afr[mt] = *(const int4v*)&Ab[frA[mt]];
      #pragma unroll
      for (int nt = 0; nt < 4; nt++) bfr[nt] = *(const int4v*)&Bb[frB[nt]];
      #pragma unroll
      for (int mt = 0; mt < 4; mt++)
        #pragma unroll
        for (int nt = 0; nt < 4; nt++)
          acc[mt][nt] = __builtin_amdgcn_mfma_i32_16x16x64_i8(afr[mt], bfr[nt], acc[mt][nt], 0, 0, 0);
    }
    __syncthreads();
  }

  if (mode == 0 || mode == 3){
    unsigned short* Ob = (unsigned short*)Cout;
    #pragma unroll
    for (int mt = 0; mt < 4; mt++){
      #pragma unroll
      for (int r = 0; r < 4; r++){
        long grow = arow + wm*64 + mt*16 + quad*4 + r;
        float sc = mean / srow[grow];
        // fold softmax scale AND log2(e): 2^-3.5 * log2(e) = 0.12751743
        if (mode == 0) sc *= 0.12751743f;
        int pos = (int)(grow & (S_-1));
        #pragma unroll
        for (int p = 0; p < 2; p++){
          int col_lo = (int)bcol + (2*wn + p)*16 + c;
          int d = col_lo & 63;
          float cv = ct[pos*64 + d], sv = st[pos*64 + d];
          float vlo = acc[mt][p][r]   * sc;
          float vhi = acc[mt][p+2][r] * sc;
          Ob[grow*(long)N + col_lo]      = f2bf(vlo*cv - vhi*sv);
          Ob[grow*(long)N + col_lo + 64] = f2bf(vhi*cv + vlo*sv);
        }
      }
    }
  } else if (mode == 1){
    #pragma unroll
    for (int mt = 0; mt < 4; mt++){
      long grow0 = arow + wm*64 + mt*16 + quad*4;
      float s0 = mean / srow[grow0];
      float s1 = mean / srow[grow0+1];
      float s2 = mean / srow[grow0+2];
      float s3 = mean / srow[grow0+3];
      long bb = grow0 >> 11; int sI = (int)(grow0 & (S_-1));
      unsigned short* base = Vt + bb*(long)KVD_*S_ + sI;
      #pragma unroll
      for (int nt = 0; nt < 4; nt++){
        float v0 = acc[mt][nt][0]*s0, v1 = acc[mt][nt][1]*s1;
        float v2 = acc[mt][nt][2]*s2, v3 = acc[mt][nt][3]*s3;
        unsigned lo, hi;
        asm("v_cvt_pk_bf16_f32 %0, %1, %2" : "=v"(lo) : "v"(v0), "v"(v1));
        asm("v_cvt_pk_bf16_f32 %0, %1, %2" : "=v"(hi) : "v"(v2), "v"(v3));
        uint2 pk; pk.x = lo; pk.y = hi;
        *(uint2*)(base + (long)(bcol + ntl[nt]*16 + c)*S_) = pk;  // 4 rows, 8B
      }
    }
  } else {
    #pragma unroll
    for (int mt = 0; mt < 4; mt++){
      #pragma unroll
      for (int r = 0; r < 4; r++){
        long grow = arow + wm*64 + mt*16 + quad*4 + r;
        float sc = mean / srow[grow];
        long cb = grow*(long)N + bcol + c;
        if (isb){
          __hip_bfloat16* o = (__hip_bfloat16*)Cout;
          #pragma unroll
          for (int nt = 0; nt < 4; nt++)
            o[cb + ntl[nt]*16] = __float2bfloat16(acc[mt][nt][r] * sc);
        } else {
          float* o = (float*)Cout;
          #pragma unroll
          for (int nt = 0; nt < 4; nt++)
            o[cb + ntl[nt]*16] = acc[mt][nt][r] * sc;
        }
      }
    }
  }
}

// ---- fused: RoPE table + weight |w| sums (blocks 0..2047)
//            + per-token activation quant of x (blocks 2048..6143) ----
__global__ void k_prep_aq(const void* x,
                          const void* Wq, const void* Wk, const void* Wv, const void* Wo,
                          float* wsum, float* ct, float* st,
                          float* srow, s8* xq){
  __shared__ __align__(16) float sh[256];
  __shared__ int dsh[4];
  int isb = detect_isb_s((const unsigned int*)x, dsh);
  int bid = blockIdx.x, t = threadIdx.x;
  if (bid < 2048){
    if (t < 64){
      float inv = exp2f(-(float)t * 0.20762050593045952f);  // 10000^(-d/64)
      float a = (float)bid * inv;
      float sn, cs; sincosf(a, &sn, &cs);
      ct[bid*64 + t] = cs; st[bid*64 + t] = sn;
    }
    if (bid < 768)       wscan_seg(Wq, (long)H_*H_,   bid,      768, isb, &wsum[0], sh);
    else if (bid < 1024) wscan_seg(Wk, (long)KVD_*H_, bid-768,  256, isb, &wsum[1], sh);
    else if (bid < 1280) wscan_seg(Wv, (long)KVD_*H_, bid-1024, 256, isb, &wsum[2], sh);
    else                 wscan_seg(Wo, (long)H_*H_,   bid-1280, 768, isb, &wsum[3], sh);
  } else {
    aquant_row_x(x, isb, bid - 2048, srow, xq, sh);
  }
}

// ---- fused ternary weight quant over all 4 weights ----
__global__ void k_wquant_all(const void* Wq, const void* Wk, const void* Wv, const void* Wo,
                             const void* x, const float* wsum,
                             s8* oq, s8* ok, s8* ov, s8* oo){
  __shared__ int dsh[4];
  int isb = detect_isb_s((const unsigned int*)x, dsh);
  int bid = blockIdx.x;
  const float cq = (float)((long)H_*H_), ck = (float)((long)KVD_*H_);
  if (bid < 1024)      wquant_seg(Wq, oq, (long)H_*H_,   bid,      1024, fmaxf(wsum[0]/cq, 1e-5f), isb);
  else if (bid < 1280) wquant_seg(Wk, ok, (long)KVD_*H_, bid-1024, 256,  fmaxf(wsum[1]/ck, 1e-5f), isb);
  else if (bid < 1536) wquant_seg(Wv, ov, (long)KVD_*H_, bid-1280, 256,  fmaxf(wsum[2]/ck, 1e-5f), isb);
  else                 wquant_seg(Wo, oo, (long)H_*H_,   bid-1536, 1024, fmaxf(wsum[3]/cq, 1e-5f), isb);
}

// ---- per-token activation quant (bf16 input: the attention output) ----
__global__ void k_aquant_bf16(const unsigned short* __restrict__ x,
                              float* __restrict__ srow, s8* __restrict__ xq){
  __shared__ __align__(16) float sh[256];
  aquant_row_ab(x, blockIdx.x, srow, xq, sh);
}

// ---- fused QKV GEMM: flat grid 768 with XCD panel clustering ----
__global__ __launch_bounds__(256, 2) void k_gemm_qkv(
      const s8* __restrict__ xq,
      const s8* __restrict__ wqq, const s8* __restrict__ wkq, const s8* __restrict__ wvq,
      const float* __restrict__ srow, const float* __restrict__ wsum,
      unsigned short* __restrict__ Qb, unsigned short* __restrict__ Kb,
      unsigned short* __restrict__ Vt,
      const float* __restrict__ ct, const float* __restrict__ st){
  __shared__ __align__(16) s8 As[2*128*64];
  __shared__ __align__(16) s8 Bs[2*128*64];
  int lid = blockIdx.x;
  int xcd = lid & 7;
  int rem = lid >> 3;          // 0..95
  int by  = xcd*4 + (rem & 3); // 0..31
  int bx  = rem >> 2;          // 0..23
  const float cq = (float)((long)H_*H_), ck = (float)((long)KVD_*H_);
  const s8* Bw; void* Cout; unsigned short* vt = nullptr;
  int N, mode; float mean; long bcol;
  if (bx < 16){
    Bw = wqq; Cout = Qb; N = H_;   mode = 0; mean = fmaxf(wsum[0]/cq, 1e-5f);  bcol = (long)bx*128;
  } else if (bx < 20){
    Bw = wkq; Cout = Kb; N = KVD_; mode = 3; mean = fmaxf(wsum[1]/ck, 1e-5f); bcol = (long)(bx-16)*128;
  } else {
    Bw = wvq; Cout = nullptr; vt = Vt; N = KVD_; mode = 1; mean = fmaxf(wsum[2]/ck, 1e-5f); bcol = (long)(bx-20)*128;
  }
  gemm_core(xq, Bw, As, Bs, srow, mean, Cout, N, mode, 0, vt, ct, st, bcol, (long)by*128);
}

// ---- output GEMM: flat grid 512 with the same clustering ----
__global__ __launch_bounds__(256, 2) void k_gemm_o(
      const s8* __restrict__ aq, const s8* __restrict__ woq,
      const float* __restrict__ srow, const float* __restrict__ wsum,
      const void* __restrict__ x, void* __restrict__ out,
      const float* __restrict__ ct, const float* __restrict__ st){
  __shared__ __align__(16) s8 As[2*128*64];
  __shared__ __align__(16) s8 Bs[2*128*64];
  __shared__ int dsh[4];
  int isb = detect_isb_s((const unsigned int*)x, dsh);
  int lid = blockIdx.x;
  int xcd = lid & 7;
  int rem = lid >> 3;          // 0..63
  int by  = xcd*4 + (rem & 3); // 0..31
  int bx  = rem >> 2;          // 0..15
  float mean = fmaxf(wsum[3] / (float)((long)H_*H_), 1e-5f);
  gemm_core(aq, woq, As, Bs, srow, mean, out, H_, 2, isb, nullptr, ct, st,
            (long)bx*128, (long)by*128);
}

// ---- MFMA flash attention: r2 configuration VERBATIM (best measured:
// 69.5us, VGPR 128, 2 blocks/CU). 7 rounds of variations all measured worse.
// Swapped QK (key-contiguous P), exp2 (log2e folded into Q), cvt_pk pairs,
// ds_write_b64 P-store; K double-buffered, V single-buffered; LDS 53KB;
// b==1 window reversal pairs big+small windows per CU.
__global__ __launch_bounds__(256) void k_attn_mfma(const unsigned short* __restrict__ Qb,
    const unsigned short* __restrict__ Kb, const unsigned short* __restrict__ Vt,
    unsigned short* __restrict__ ob){
  int wid = threadIdx.x >> 6, lane = threadIdx.x & 63;
  int quad = lane >> 4, c = lane & 15;
  int kvh = blockIdx.y, b = blockIdx.z;
  int win = blockIdx.x;
  if (b == 1) win = (S_/32 - 1) - win;   // pair big+small windows per CU
  int h = kvh*4 + wid;
  int q0 = win*32;

  __shared__ __align__(16) unsigned short Ks[2][64*128];
  __shared__ __align__(16) unsigned short Vs[128*64];
  __shared__ __align__(16) unsigned short Ps[4][16*PSTR];

  short8 qf[2][4];
  #pragma unroll
  for (int t0 = 0; t0 < 2; t0++)
    #pragma unroll
    for (int f = 0; f < 4; f++)
      qf[t0][f] = *(const short8*)(Qb + ((long)(b*S_ + q0 + t0*16 + c)*NH_ + h)*HD_ + f*32 + quad*8);

  const unsigned short* Kg = Kb + (long)b*S_*KVD_ + kvh*HD_;
  const unsigned short* Vg = Vt + ((long)b*KVD_ + kvh*HD_)*S_;

  f32x4 o[2][8], ol[2];
  #pragma unroll
  for (int t0 = 0; t0 < 2; t0++){
    #pragma unroll
    for (int i = 0; i < 8; i++) o[t0][i] = (f32x4){0.f,0.f,0.f,0.f};
    ol[t0] = (f32x4){0.f,0.f,0.f,0.f};
  }
  short8 ones;
  #pragma unroll
  for (int i = 0; i < 8; i++) ones[i] = (short)0x3F80;

  int skey = lane >> 4;
  int kslot = lane & 15;
  int vrow = lane >> 3;
  int vslot = lane & 7;

  int nk = q0 + 32;
  // prologue: stage K(0) -> Ks[0]
  #pragma unroll
  for (int i = 0; i < 4; i++){
    int kk = wid*16 + i*4;
    int key = kk + skey;
    int g = kslot ^ (key & 15);
    gl2lds16(Kg + (long)key*KVD_ + g*8, &Ks[0][kk*128]);
  }

  int buf = 0;
  for (int kc = 0; kc < nk; kc += 64, buf ^= 1){
    __syncthreads();   // A: K(kc) staged; all waves done with prior Vs reads
    // stage V(kc) — latency hidden by QK phase below
    #pragma unroll
    for (int i = 0; i < 4; i++){
      int rr = wid*32 + i*8;
      int hd = rr + vrow;
      int g = vslot ^ (hd & 7);
      gl2lds16(Vg + (long)hd*S_ + kc + g*8, &Vs[rr*64]);
    }

    // ---- QK^T from Ks[buf], SWAPPED: s[t0][kt] = K_tile^T x Q_tile
    f32x4 s[2][4];
    #pragma unroll
    for (int t0 = 0; t0 < 2; t0++)
      #pragma unroll
      for (int kt = 0; kt < 4; kt++) s[t0][kt] = (f32x4){0.f,0.f,0.f,0.f};
    #pragma unroll
    for (int kt = 0; kt < 4; kt++){
      short8 kf4[4];
      #pragma unroll
      for (int f = 0; f < 4; f++)
        kf4[f] = *(const short8*)&Ks[buf][(kt*16 + c)*128 + ((f*4 + quad) ^ c)*8];
      #pragma unroll
      for (int t0 = 0; t0 < 2; t0++)
        #pragma unroll
        for (int f = 0; f < 4; f++)
          s[t0][kt] = __builtin_amdgcn_mfma_f32_16x16x32_bf16(kf4[f], qf[t0][f], s[t0][kt], 0, 0, 0);
    }
    // causal mask in transposed layout
    #pragma unroll
    for (int t0 = 0; t0 < 2; t0++){
      int qv = q0 + t0*16 + c;
      if (kc + 63 > q0 + t0*16){
        #pragma unroll
        for (int kt = 0; kt < 4; kt++){
          #pragma unroll
          for (int r = 0; r < 4; r++){
            int key = kc + kt*16 + quad*4 + r;
            if (key > qv) s[t0][kt][r] = -1e30f;
          }
        }
      }
    }

    __syncthreads();   // B: V(kc) staged (hidden by QK above)

    // prefetch K(kc+64) -> Ks[buf^1]; drained at next barrier A (hidden by PV)
    if (kc + 64 < nk){
      #pragma unroll
      for (int i = 0; i < 4; i++){
        int kk = wid*16 + i*4;
        int key = kk + skey;
        int g = kslot ^ (key & 15);
        gl2lds16(Kg + (long)(kc + 64 + key)*KVD_ + g*8, &Ks[buf^1][kk*128]);
      }
    }

    // ---- exp2 + packed P write + PV
    #pragma unroll
    for (int pp = 0; pp < 2; pp++){
      short8 vf[8];
      #pragma unroll
      for (int nt = 0; nt < 8; nt++)
        vf[nt] = *(const short8*)&Vs[(nt*16 + c)*64 + ((pp*4 + quad) ^ (c & 7))*8];
      #pragma unroll
      for (int t0 = 0; t0 < 2; t0++){
        #pragma unroll
        for (int tk = 0; tk < 2; tk++){
          f32x4 sv = s[t0][pp*2 + tk];
          float e0 = exp2f(sv[0]), e1 = exp2f(sv[1]);
          float e2 = exp2f(sv[2]), e3 = exp2f(sv[3]);
          unsigned w0, w1;
          asm("v_cvt_pk_bf16_f32 %0, %1, %2" : "=v"(w0) : "v"(e0), "v"(e1));
          asm("v_cvt_pk_bf16_f32 %0, %1, %2" : "=v"(w1) : "v"(e2), "v"(e3));
          uint2 pkv; pkv.x = w0; pkv.y = w1;
          // 4 consecutive keys for q-row c -> one 8B store
          *(uint2*)&Ps[wid][c*PSTR + tk*16 + quad*4] = pkv;
        }
        short8 pf = *(const short8*)&Ps[wid][c*PSTR + quad*8];
        #pragma unroll
        for (int nt = 0; nt < 8; nt++)
          o[t0][nt] = __builtin_amdgcn_mfma_f32_16x16x32_bf16(pf, vf[nt], o[t0][nt], 0, 0, 0);
        ol[t0] = __builtin_amdgcn_mfma_f32_16x16x32_bf16(pf, ones, ol[t0], 0, 0, 0);
      }
    }
  }

  #pragma unroll
  for (int t0 = 0; t0 < 2; t0++){
    float il[4];
    #pragma unroll
    for (int r = 0; r < 4; r++) il[r] = 1.0f / ol[t0][r];
    #pragma unroll
    for (int nt = 0; nt < 8; nt++)
      #pragma unroll
      for (int r = 0; r < 4; r++)
        ob[((long)(b*S_ + q0 + t0*16 + quad*4 + r))*H_ + h*HD_ + nt*16 + c] = f2bf(o[t0][nt][r]*il[r]);
  }
}

extern "C" void kernel_launch(void* const* d_in, const int* in_sizes, int n_in,
                              void* d_out, int out_size, void* d_ws, size_t ws_size,
                              hipStream_t stream){
  (void)in_sizes; (void)n_in; (void)out_size; (void)ws_size;
  const void* x  = d_in[0];
  const void* Wq = d_in[2];
  const void* Wk = d_in[3];
  const void* Wv = d_in[4];
  const void* Wo = d_in[5];
  char* ws = (char*)d_ws;
  size_t o = 0;
  auto alloc = [&](size_t b){ size_t r = o; o += (b + 255) & ~(size_t)255; return r; };
  size_t META = alloc(256);
  float* wsum = (float*)(ws + META);
  float* s_x = (float*)(ws + alloc((size_t)M_*4));
  float* s_a = (float*)(ws + alloc((size_t)M_*4));
  float* ct  = (float*)(ws + alloc((size_t)S_*64*4));
  float* st  = (float*)(ws + alloc((size_t)S_*64*4));
  s8* xq  = (s8*)(ws + alloc((size_t)M_*H_));
  s8* wqq = (s8*)(ws + alloc((size_t)H_*H_));
  s8* wkq = (s8*)(ws + alloc((size_t)KVD_*H_));
  s8* wvq = (s8*)(ws + alloc((size_t)KVD_*H_));
  s8* woq = (s8*)(ws + alloc((size_t)H_*H_));
  unsigned short* Qb = (unsigned short*)(ws + alloc((size_t)M_*NH_*HD_*2));
  unsigned short* Kb = (unsigned short*)(ws + alloc((size_t)M_*KVD_*2));
  unsigned short* Vt = (unsigned short*)(ws + alloc((size_t)M_*KVD_*2));
  unsigned short* ab = (unsigned short*)(ws + alloc((size_t)M_*H_*2));
  s8* aq = xq;   // xq dead after QKV GEMM

  hipMemsetAsync(ws + META, 0, 64, stream);

  k_prep_aq<<<2048 + M_, 256, 0, stream>>>(x, Wq, Wk, Wv, Wo, wsum, ct, st, s_x, xq);
  k_wquant_all<<<2560, 256, 0, stream>>>(Wq, Wk, Wv, Wo, x, wsum, wqq, wkq, wvq, woq);
  k_gemm_qkv<<<768, 256, 0, stream>>>(xq, wqq, wkq, wvq, s_x, wsum, Qb, Kb, Vt, ct, st);
  dim3 ga(S_/32, NKV_, B_);
  k_attn_mfma<<<ga, 256, 0, stream>>>(Qb, Kb, Vt, ab);
  k_aquant_bf16<<<M_, 256, 0, stream>>>(ab, s_a, aq);
  k_gemm_o<<<512, 256, 0, stream>>>(aq, woq, s_a, wsum, x, d_out, ct, st);
}